// Round 4
// baseline (585.457 us; speedup 1.0000x reference)
//
#include <hip/hip_runtime.h>
#include <cstdint>
#include <cstddef>

typedef unsigned int   u32;
typedef unsigned short u16;
typedef float v2f __attribute__((ext_vector_type(2)));

__device__ __forceinline__ float bf2f(u32 bits16) { return __uint_as_float(bits16 << 16); }
__device__ __forceinline__ u16 f2bf(float f) {
  u32 u = __float_as_uint(f);
  u = u + 0x7FFFu + ((u >> 16) & 1u);   // round-to-nearest-even
  return (u16)(u >> 16);
}
__device__ __forceinline__ u32 pk(float a, float b) {
  return (u32)f2bf(a) | ((u32)f2bf(b) << 16);
}
__device__ __forceinline__ float lo16(u32 w) { return bf2f(w & 0xFFFFu); }
__device__ __forceinline__ float hi16(u32 w) { return bf2f(w >> 16); }
__device__ __forceinline__ float frcp(float x) { return __builtin_amdgcn_rcpf(x); }

__device__ __forceinline__ v2f vfma2(v2f a, v2f b, v2f c) { return __builtin_elementwise_fma(a, b, c); }
__device__ __forceinline__ v2f vrcp2(v2f x) { v2f r; r.x = frcp(x.x); r.y = frcp(x.y); return r; }
__device__ __forceinline__ v2f vexp22(v2f x) { v2f r; r.x = exp2f(x.x); r.y = exp2f(x.y); return r; }

#define NL2E  (-1.4426950408889634f)
#define TWOL2E (2.8853900817779268f)

__device__ __forceinline__ int load_idx(const int* eidx, int is64, long long pos) {
  if (is64) return (int)(((const long long*)eidx)[pos]);
  return eidx[pos];
}

// ---- prep stage 1 (grid 34): WcTmp = Wvl_left @ Wvv, edge-width detect, bc ----
__global__ void k_prep1(const float* Wvl, const float* Wvv,
                        const float* bvv, const float* bvl,
                        const int* eidx, int E, int* flag,
                        float* WcTmp, float* bc) {
  int b = blockIdx.x, tid = threadIdx.x;
  if (b < 32) {
    int c = 2 * b + (tid >> 7), kk = tid & 127;
    float s = 0.f;
    for (int m = 0; m < 64; ++m) s += Wvl[c * 128 + m] * Wvv[m * 128 + kk];
    WcTmp[c * 128 + kk] = s;
  } else if (b == 32) {
    __shared__ int zc;
    if (tid == 0) zc = 0;
    __syncthreads();
    int n = (E < 1024) ? E : 1024;
    int local = 0;
    for (int i = tid; i < n; i += 256) {
      if (eidx[2 * i + 1] == 0) local++;   // high words if int64 (all 0)
    }
    atomicAdd(&zc, local);
    __syncthreads();
    if (tid == 0) *flag = (zc >= (n >> 1)) ? 1 : 0;
  } else if (b == 33) {
    if (tid < 64) {
      float s = 0.f;
      for (int m = 0; m < 64; ++m) s += Wvl[tid * 128 + m] * bvv[m];
      bc[tid] = s + bvl[tid];
    }
  }
}

// ---- prep stage 2 (grid 11): bf16 epilogue tables + interleaved GEMM weight table ----
// Wsl2[(g*64+c)*2+h] = pack(Wsl[c][4g+2h], Wsl[c][4g+2h+1]), g<32
// Wpk : 2048 u32 : Wvl_right packed, same (g,c,h) layout, g<16
// WTall[((y*64+k)*64+c)*4+m]: m0=Wss[c][64y+k] m1=Wsv[..] m2=Wvs[..] m3=WcTmp[..]
__global__ void k_prep2(const float* Wss, const float* Wsv, const float* Wvs,
                        const float* Wsl, const float* Wvl, const float* WcTmp,
                        u32* Wsl2, u32* Wpk, float* WTall) {
  int b = blockIdx.x, tid = threadIdx.x;
  if (b < 2) {
    for (int i = 0; i < 8; ++i) {
      int o = b * 2048 + i * 256 + tid;
      int h = o & 1, c = (o >> 1) & 63, g = o >> 7;
      int k = 4 * g + 2 * h;
      Wsl2[o] = pk(Wsl[c * 128 + k], Wsl[c * 128 + k + 1]);
    }
  } else if (b == 2) {
    for (int i = 0; i < 8; ++i) {
      int o = i * 256 + tid;
      int h = o & 1, c = (o >> 1) & 63, g = o >> 7;
      int k = 4 * g + 2 * h;
      Wpk[o] = pk(Wvl[c * 128 + 64 + k], Wvl[c * 128 + 64 + k + 1]);
    }
  } else {
    for (int i = 0; i < 16; ++i) {
      int o = (b - 3) * 4096 + i * 256 + tid;
      int m = o & 3, c = (o >> 2) & 63, k = (o >> 8) & 63, y = o >> 14;
      int src = c * 128 + 64 * y + k;
      float v;
      if (m == 0)      v = Wss[src];
      else if (m == 1) v = Wsv[src];
      else if (m == 2) v = Wvs[src];
      else             v = WcTmp[src];
      WTall[o] = v;
    }
  }
}

__global__ void k_deg(const int* eidx, const int* flag, const float* attr,
                      float* deg, int* cnt, int E) {
  int e = blockIdx.x * 256 + threadIdx.x;
  if (e >= E) return;
  int is64 = *flag;
  int col = load_idx(eidx, is64, (long long)E + e);
  atomicAdd(&deg[col], attr[e]);
  atomicAdd(&cnt[col], 1);
}

// ---- multi-block exclusive scan of cnt -> rowptr, cursor ----
__global__ void k_scan_red(const int* cnt, int* blocksum, int N) {
  __shared__ int lds[256];
  int tid = threadIdx.x, idx = blockIdx.x * 256 + tid;
  lds[tid] = (idx < N) ? cnt[idx] : 0;
  __syncthreads();
  for (int off = 128; off > 0; off >>= 1) {
    if (tid < off) lds[tid] += lds[tid + off];
    __syncthreads();
  }
  if (tid == 0) blocksum[blockIdx.x] = lds[0];
}

__global__ void k_scan_mid(const int* blocksum, int* blockoff, int NB, int* rowptr, int N, int E) {
  __shared__ int lds[1024];
  int tid = threadIdx.x;
  int v = (tid < NB) ? blocksum[tid] : 0;
  lds[tid] = v;
  __syncthreads();
  for (int off = 1; off < 1024; off <<= 1) {
    int t = (tid >= off) ? lds[tid - off] : 0;
    __syncthreads();
    lds[tid] += t;
    __syncthreads();
  }
  if (tid < NB) blockoff[tid] = lds[tid] - v;   // exclusive
  if (tid == 0) rowptr[N] = E;
}

__global__ void k_scan_out(const int* cnt, const int* blockoff, int* rowptr, int* cursor, int N) {
  __shared__ int lds[256];
  int tid = threadIdx.x, idx = blockIdx.x * 256 + tid;
  int v = (idx < N) ? cnt[idx] : 0;
  lds[tid] = v;
  __syncthreads();
  for (int off = 1; off < 256; off <<= 1) {
    int t = (tid >= off) ? lds[tid - off] : 0;
    __syncthreads();
    lds[tid] += t;
    __syncthreads();
  }
  if (idx < N) {
    int o = blockoff[blockIdx.x] + lds[tid] - v;
    rowptr[idx] = o;
    cursor[idx] = o;
  }
}

// CSR fill: erecA[p]={norm, dx, dy, dz} (d = pos_i - pos_j), erecI[p]=row
__global__ void k_fill(const int* eidx, const int* flag, const float* attr, const float* deg,
                       const float* pos, int* cursor, float4* erecA, int* erecI, int E) {
  int e = blockIdx.x * 256 + threadIdx.x;
  if (e >= E) return;
  int is64 = *flag;
  int r  = load_idx(eidx, is64, e);
  int cl = load_idx(eidx, is64, (long long)E + e);
  float dr = deg[r], dc = deg[cl];
  float disr = (dr > 0.f) ? rsqrtf(dr) : 0.f;
  float disc = (dc > 0.f) ? rsqrtf(dc) : 0.f;
  float nrm = disr * disc * attr[e];
  float dx = pos[cl * 3 + 0] - pos[r * 3 + 0];
  float dy = pos[cl * 3 + 1] - pos[r * 3 + 1];
  float dz = pos[cl * 3 + 2] - pos[r * 3 + 2];
  int p = atomicAdd(&cursor[cl], 1);
  erecA[p] = make_float4(nrm, dx, dy, dz);
  erecI[p] = r;
}

// Fused node GEMM, both sides in one block (X staged once).
// grid ceil(N/16): block = 16 nodes, 256 threads. Thread (nl=tid>>4, cg=tid&15)
// owns 1 node x channels {cg,16+cg,32+cg,48+cg}. Per y-phase: 32 accums, per-y store.
// LDS: X [4comp][16n][68] fp32 (17.4KB) + W 16k-chunk [16][64] float4 (16KB) = 33.8KB
// -> 4 blocks/CU (50% occ). W streamed in 8 chunks (2y x 4kc).
__global__ __launch_bounds__(256) void k_gemm_rec(
    const float* __restrict__ scalar, const float* __restrict__ vector,
    const float* __restrict__ WTall,
    uint4* __restrict__ rec_i4, uint4* __restrict__ rec_j4, int N) {
  __shared__ float Xs[4][16][68];   // 17408 B
  __shared__ float4 Wch[16 * 64];   // 16384 B
  int tid = threadIdx.x;
  int nb = blockIdx.x * 16;
  {
    int n = tid >> 4, kq = tid & 15;
    float4 v = make_float4(0.f, 0.f, 0.f, 0.f);
    if (nb + n < N) v = *(const float4*)(scalar + (size_t)(nb + n) * 64 + 4 * kq);
    *(float4*)&Xs[0][n][4 * kq] = v;
  }
  #pragma unroll
  for (int i = 0; i < 3; ++i) {
    int q = tid + i * 256;
    int r = q >> 4, kq = q & 15;
    int n = r / 3, d = r - n * 3;
    float4 v = make_float4(0.f, 0.f, 0.f, 0.f);
    if (nb + n < N) v = *(const float4*)(vector + (size_t)(nb + n) * 192 + d * 64 + 4 * kq);
    *(float4*)&Xs[1 + d][n][4 * kq] = v;
  }
  int cg = tid & 15, nl = tid >> 4;
  int node = nb + nl;
  #pragma unroll
  for (int y = 0; y < 2; ++y) {
    float aA[4] = {}, aC[4] = {}, aB[3][4] = {}, aP[3][4] = {};
    const float4* Wg = (const float4*)WTall + (size_t)y * 4096;
    for (int kc = 0; kc < 4; ++kc) {
      __syncthreads();   // Wch free to overwrite (also covers X staging, 1st iter)
      #pragma unroll
      for (int i = 0; i < 4; ++i) Wch[i * 256 + tid] = Wg[kc * 1024 + i * 256 + tid];
      __syncthreads();
      for (int k4 = 0; k4 < 16; k4 += 4) {
        int kg = kc * 16 + k4;
        float4 x0 = *(const float4*)&Xs[0][nl][kg];
        float4 x1 = *(const float4*)&Xs[1][nl][kg];
        float4 x2 = *(const float4*)&Xs[2][nl][kg];
        float4 x3 = *(const float4*)&Xs[3][nl][kg];
        #pragma unroll
        for (int t = 0; t < 4; ++t) {
          float xsv = (t == 0) ? x0.x : (t == 1) ? x0.y : (t == 2) ? x0.z : x0.w;
          float xv0 = (t == 0) ? x1.x : (t == 1) ? x1.y : (t == 2) ? x1.z : x1.w;
          float xv1 = (t == 0) ? x2.x : (t == 1) ? x2.y : (t == 2) ? x2.z : x2.w;
          float xv2 = (t == 0) ? x3.x : (t == 1) ? x3.y : (t == 2) ? x3.z : x3.w;
          #pragma unroll
          for (int j = 0; j < 4; ++j) {
            float4 w = Wch[(k4 + t) * 64 + 16 * j + cg];
            aA[j]    = fmaf(xsv, w.x, aA[j]);
            aC[j]    = fmaf(xsv, w.y, aC[j]);
            aB[0][j] = fmaf(xv0, w.z, aB[0][j]);
            aB[1][j] = fmaf(xv1, w.z, aB[1][j]);
            aB[2][j] = fmaf(xv2, w.z, aB[2][j]);
            aP[0][j] = fmaf(xv0, w.w, aP[0][j]);
            aP[1][j] = fmaf(xv1, w.w, aP[1][j]);
            aP[2][j] = fmaf(xv2, w.w, aP[2][j]);
          }
        }
      }
    }
    if (node < N) {
      uint4* dst = y ? rec_j4 : rec_i4;
      #pragma unroll
      for (int j = 0; j < 4; ++j) {
        int c = 16 * j + cg;
        uint4 o;
        o.x = pk(aA[j], aC[j]);
        o.y = pk(aB[0][j], aB[1][j]);
        o.z = pk(aB[2][j], aP[0][j]);
        o.w = pk(aP[1][j], aP[2][j]);
        dst[(size_t)node * 64 + c] = o;
      }
    }
  }
}

// Fused hot kernel: one wave per node, 2-edge unrolled loop with double prefetch,
// packed-fp32 (v2f -> v_pk_*_f32) edge math across the edge pair, in-wave epilogue.
__global__ __launch_bounds__(512) void k_edges(
    const u16* __restrict__ rec_i, const u16* __restrict__ rec_j,
    const float4* __restrict__ erecA, const int* __restrict__ erecI,
    const int* __restrict__ rowptr,
    const float* __restrict__ scalar, const float* __restrict__ vector,
    const float* __restrict__ bss, const float* __restrict__ bvs,
    const float* __restrict__ bsv, const float* __restrict__ bsl,
    const u32* __restrict__ Wsl2g, const u32* __restrict__ Wpkg,
    const float* __restrict__ bcg,
    float* __restrict__ out_s, float* __restrict__ out_v, int N) {
  __shared__ u32 sWsl[4096];        // 16 KB
  __shared__ u32 sWv[2048];         // 8 KB  (Wvl_right only)
  __shared__ float sStage[8 * 128]; // 4 KB, wave-private epilogue stage
  int tid = threadIdx.x, lane = tid & 63, wv = tid >> 6;
  for (int o = tid; o < 4096; o += 512) sWsl[o] = Wsl2g[o];
  for (int o = tid; o < 2048; o += 512) sWv[o] = Wpkg[o];
  __syncthreads();   // the only block barrier

  int node = __builtin_amdgcn_readfirstlane((int)(blockIdx.x * 8) + wv);
  if (node >= N) node = N - 1;

  uint4 riv = *(const uint4*)(rec_i + ((size_t)node << 9) + lane * 8);
  float aiB  = lo16(riv.x) + bss[lane];
  float KciB = TWOL2E * (hi16(riv.x) + bsv[lane]);
  float Bvs  = bvs[lane];
  float bib0 = lo16(riv.y) + Bvs;
  float bib1 = hi16(riv.y) + Bvs;
  float bib2 = lo16(riv.z) + Bvs;
  float Pi0  = hi16(riv.z), Pi1 = lo16(riv.w), Pi2 = hi16(riv.w);
  float bsl_c = bsl[lane], bc_c = bcg[lane];

  const v2f vm2 = {-2.f, -2.f}, vone = {1.f, 1.f};
  v2f aiB2 = {aiB, aiB}, KciB2 = {KciB, KciB};
  v2f bib02 = {bib0, bib0}, bib12 = {bib1, bib1}, bib22 = {bib2, bib2};
  v2f us2 = {0,0}, uv2 = {0,0}, t02 = {0,0}, t12 = {0,0}, t22 = {0,0};
  v2f g02 = {0,0}, g12 = {0,0}, g22 = {0,0}, wa2 = {0,0};

  int rp = rowptr[node], re = rowptr[node + 1];
  u32 lane16 = (u32)lane << 4;
  const char* rjb = (const char*)rec_j;

  // erecI has 64 zeroed ints of slack past E -> prefetch reads are always valid
  u32 ra = (u32)erecI[rp];
  u32 rb = (u32)erecI[rp + 1];
  uint4 pre0 = *(const uint4*)(rjb + ((ra << 10) + lane16));
  uint4 pre1 = *(const uint4*)(rjb + ((rb << 10) + lane16));
  int p = rp;
  for (; p + 1 < re; p += 2) {
    uint4 c0 = pre0, c1 = pre1;
    u32 rn0 = (u32)erecI[p + 2];
    u32 rn1 = (u32)erecI[p + 3];
    pre0 = *(const uint4*)(rjb + ((rn0 << 10) + lane16));
    pre1 = *(const uint4*)(rjb + ((rn1 << 10) + lane16));
    float4 e0 = erecA[p];
    float4 e1 = erecA[p + 1];

    v2f aj  = {lo16(c0.x), lo16(c1.x)};
    v2f cj  = {hi16(c0.x), hi16(c1.x)};
    v2f bj0 = {lo16(c0.y), lo16(c1.y)};
    v2f bj1 = {hi16(c0.y), hi16(c1.y)};
    v2f bj2 = {lo16(c0.z), lo16(c1.z)};
    v2f rj0 = {hi16(c0.z), hi16(c1.z)};
    v2f rj1 = {lo16(c0.w), lo16(c1.w)};
    v2f rj2 = {hi16(c0.w), hi16(c1.w)};
    v2f nrm = {e0.x, e1.x}, dx = {e0.y, e1.y}, dy = {e0.z, e1.z}, dz = {e0.w, e1.w};

    v2f xs  = aiB2 + aj;
    v2f s2s = xs * vrcp2(vone + vexp22(xs * NL2E));
    v2f yv  = (bib02 + bj0) * dx;
    yv = vfma2(bib12 + bj1, dy, yv);
    yv = vfma2(bib22 + bj2, dz, yv);
    v2f v2s = yv * vrcp2(vone + vexp22(yv * NL2E));
    v2f qh  = vfma2(cj, (v2f){TWOL2E, TWOL2E}, KciB2);
    v2f th0 = vfma2(vm2, vrcp2(vone + vexp22(qh * dx)), vone);
    v2f th1 = vfma2(vm2, vrcp2(vone + vexp22(qh * dy)), vone);
    v2f th2 = vfma2(vm2, vrcp2(vone + vexp22(qh * dz)), vone);
    us2 = vfma2(nrm, s2s, us2); uv2 = vfma2(nrm, v2s, uv2);
    t02 = vfma2(nrm, th0, t02); t12 = vfma2(nrm, th1, t12); t22 = vfma2(nrm, th2, t22);
    g02 = vfma2(nrm, rj0, g02); g12 = vfma2(nrm, rj1, g12); g22 = vfma2(nrm, rj2, g22);
    wa2 += nrm;
  }
  if (p < re) {
    uint4 c0 = pre0;
    float4 e0 = erecA[p];
    float nrm = e0.x, dx = e0.y, dy = e0.z, dz = e0.w;
    float aj  = lo16(c0.x), cjs = hi16(c0.x);
    float bj0 = lo16(c0.y), bj1 = hi16(c0.y), bj2 = lo16(c0.z);
    float rj0 = hi16(c0.z), rj1 = lo16(c0.w), rj2 = hi16(c0.w);
    float xs  = aiB + aj;
    float s2s = xs * frcp(1.f + exp2f(xs * NL2E));
    float yv  = (bib0 + bj0) * dx;
    yv = fmaf(bib1 + bj1, dy, yv);
    yv = fmaf(bib2 + bj2, dz, yv);
    float v2s = yv * frcp(1.f + exp2f(yv * NL2E));
    float qh  = fmaf(TWOL2E, cjs, KciB);
    float th0 = fmaf(-2.f, frcp(1.f + exp2f(qh * dx)), 1.f);
    float th1 = fmaf(-2.f, frcp(1.f + exp2f(qh * dy)), 1.f);
    float th2 = fmaf(-2.f, frcp(1.f + exp2f(qh * dz)), 1.f);
    us2.x = fmaf(nrm, s2s, us2.x); uv2.x = fmaf(nrm, v2s, uv2.x);
    t02.x = fmaf(nrm, th0, t02.x); t12.x = fmaf(nrm, th1, t12.x); t22.x = fmaf(nrm, th2, t22.x);
    g02.x = fmaf(nrm, rj0, g02.x); g12.x = fmaf(nrm, rj1, g12.x); g22.x = fmaf(nrm, rj2, g22.x);
    wa2.x += nrm;
  }
  float us = us2.x + us2.y, uv = uv2.x + uv2.y;
  float t0 = t02.x + t02.y, t1 = t12.x + t12.y, t2 = t22.x + t22.y;
  float g0 = g02.x + g02.y, g1 = g12.x + g12.y, g2 = g22.x + g22.y;
  float wa = wa2.x + wa2.y;

  // ---- epilogue: scalar head (wave-local, no block barrier) ----
  float* mys = &sStage[wv * 128];
  mys[lane] = us; mys[64 + lane] = uv;
  __threadfence_block();
  float acc = wa * bsl_c;
  #pragma unroll
  for (int g = 0; g < 32; ++g) {
    float4 u = *(const float4*)&mys[4 * g];
    uint2 w = *(const uint2*)&sWsl[(g * 64 + lane) * 2];
    acc = fmaf(u.x, lo16(w.x), acc);
    acc = fmaf(u.y, hi16(w.x), acc);
    acc = fmaf(u.z, lo16(w.y), acc);
    acc = fmaf(u.w, hi16(w.y), acc);
  }
  size_t so = ((size_t)node << 6) + lane;
  out_s[so] = acc * frcp(1.f + exp2f(acc * NL2E)) + scalar[so];

  // ---- epilogue: vector head (t-part matvec only; x,y parts precomputed) ----
  float gg[3] = {g0, g1, g2}, tt[3] = {t0, t1, t2}, Pi[3] = {Pi0, Pi1, Pi2};
  #pragma unroll
  for (int d = 0; d < 3; ++d) {
    size_t vo = (((size_t)node * 3 + d) << 6) + lane;
    float vid = vector[vo];
    __threadfence_block();
    mys[lane] = tt[d];
    __threadfence_block();
    float a2 = fmaf(wa, bc_c + Pi[d], gg[d]);
    #pragma unroll
    for (int g = 0; g < 16; ++g) {
      float4 tu = *(const float4*)&mys[4 * g];
      uint2 w = *(const uint2*)&sWv[(g * 64 + lane) * 2];
      a2 = fmaf(tu.x, lo16(w.x), a2); a2 = fmaf(tu.y, hi16(w.x), a2);
      a2 = fmaf(tu.z, lo16(w.y), a2); a2 = fmaf(tu.w, hi16(w.y), a2);
    }
    float th = fmaf(-2.f, frcp(1.f + exp2f(TWOL2E * a2)), 1.f);
    out_v[vo] = th + vid;
  }
}

extern "C" void kernel_launch(void* const* d_in, const int* in_sizes, int n_in,
                              void* d_out, int out_size, void* d_ws, size_t ws_size,
                              hipStream_t stream) {
  const float* scalar   = (const float*)d_in[0];
  const float* vector   = (const float*)d_in[1];
  const float* position = (const float*)d_in[2];
  const int*   eidx     = (const int*)d_in[3];
  const float* attr     = (const float*)d_in[4];
  const float* Wss = (const float*)d_in[5];
  const float* bss = (const float*)d_in[6];
  const float* Wvs = (const float*)d_in[7];
  const float* bvs = (const float*)d_in[8];
  const float* Wsl = (const float*)d_in[9];
  const float* bsl = (const float*)d_in[10];
  const float* Wsv = (const float*)d_in[11];
  const float* bsv = (const float*)d_in[12];
  const float* Wvv = (const float*)d_in[13];
  const float* bvv = (const float*)d_in[14];
  const float* Wvl = (const float*)d_in[15];
  const float* bvl = (const float*)d_in[16];

  int N = in_sizes[0] / 64;
  int E = in_sizes[4];
  int NB = (N + 255) / 256;   // scan blocks (must be <= 1024)

  char* wsb = (char*)d_ws;
  size_t off = 0;
  auto alloc = [&](size_t bytes) -> char* {
    char* p = wsb + off;
    off += (bytes + 255) & ~(size_t)255;
    return p;
  };
  float*  deg    = (float*)alloc((size_t)N * 4);
  int*    cnt    = (int*)alloc((size_t)N * 4);
  int*    rowptr = (int*)alloc((size_t)(N + 1) * 4);
  int*    cursor = (int*)alloc((size_t)N * 4);
  int*    blocksum = (int*)alloc((size_t)NB * 4);
  int*    blockoff = (int*)alloc((size_t)NB * 4);
  float4* erecA  = (float4*)alloc((size_t)E * 16);
  int*    erecI  = (int*)alloc((size_t)(E + 64) * 4);   // +slack for prefetch reads
  u16*    rec_i  = (u16*)alloc((size_t)N * 512 * 2);
  u16*    rec_j  = (u16*)alloc((size_t)N * 512 * 2);
  float*  WTall  = (float*)alloc(2 * 64 * 64 * 4 * 4);  // 128 KB interleaved weights
  u32*    Wsl2   = (u32*)alloc(4096 * 4);
  u32*    Wpk    = (u32*)alloc(2048 * 4);
  float*  WcTmp  = (float*)alloc(64 * 128 * 4);
  float*  bc     = (float*)alloc(64 * 4);
  int*    flag   = (int*)alloc(4);
  (void)ws_size; (void)n_in; (void)out_size;

  // zero deg + cnt (contiguous region) and the erecI prefetch slack
  hipMemsetAsync(deg, 0, (size_t)((char*)rowptr - (char*)deg), stream);
  hipMemsetAsync(erecI + E, 0, 64 * 4, stream);

  k_prep1<<<34, 256, 0, stream>>>(Wvl, Wvv, bvv, bvl, eidx, E, flag, WcTmp, bc);
  k_prep2<<<11, 256, 0, stream>>>(Wss, Wsv, Wvs, Wsl, Wvl, WcTmp, Wsl2, Wpk, WTall);
  k_deg<<<(E + 255) / 256, 256, 0, stream>>>(eidx, flag, attr, deg, cnt, E);
  k_scan_red<<<NB, 256, 0, stream>>>(cnt, blocksum, N);
  k_scan_mid<<<1, 1024, 0, stream>>>(blocksum, blockoff, NB, rowptr, N, E);
  k_scan_out<<<NB, 256, 0, stream>>>(cnt, blockoff, rowptr, cursor, N);
  k_fill<<<(E + 255) / 256, 256, 0, stream>>>(eidx, flag, attr, deg, position, cursor, erecA, erecI, E);
  k_gemm_rec<<<(N + 15) / 16, 256, 0, stream>>>(scalar, vector, WTall,
                                                (uint4*)rec_i, (uint4*)rec_j, N);
  k_edges<<<(N + 7) / 8, 512, 0, stream>>>(rec_i, rec_j, erecA, erecI, rowptr,
                                           scalar, vector, bss, bvs, bsv, bsl,
                                           Wsl2, Wpk, bc,
                                           (float*)d_out, (float*)d_out + (size_t)N * 64, N);
}